// Round 1
// baseline (3325.396 us; speedup 1.0000x reference)
//
#include <hip/hip_runtime.h>
#include <cmath>

#define N_NODES   100000
#define N_EDGES   1600000
#define N_FEATS   128
#define HIDDEN    64
#define N_CLASSES 40
#define N_LAYERS  8
#define ALPHA     0.1f
#define LAMDA     0.5f

// ---------------- gcn_norm ----------------

__global__ __launch_bounds__(256) void k_init_deg(float* __restrict__ deg) {
    int i = blockIdx.x * 256 + threadIdx.x;
    if (i < N_NODES) deg[i] = 1.0f;   // self-loop contributes 1
}

__global__ __launch_bounds__(256) void k_count_deg(const int* __restrict__ col,
                                                   float* __restrict__ deg) {
    int e = blockIdx.x * 256 + threadIdx.x;
    if (e < N_EDGES) unsafeAtomicAdd(&deg[col[e]], 1.0f);
}

__global__ __launch_bounds__(256) void k_dinv(float* __restrict__ deg) {
    int i = blockIdx.x * 256 + threadIdx.x;
    if (i < N_NODES) deg[i] = 1.0f / sqrtf(deg[i]);   // deg >= 1 always
}

__global__ __launch_bounds__(256) void k_norm(const int* __restrict__ row,
                                              const int* __restrict__ col,
                                              const float* __restrict__ dinv,
                                              float* __restrict__ norm) {
    int e = blockIdx.x * 256 + threadIdx.x;
    if (e < N_EDGES) norm[e] = dinv[row[e]] * dinv[col[e]];
}

// ---------------- input GEMM: h = relu(x @ W0 + b0), h0 = h ----------------
// 64 rows per block, 256 threads, W0 (128x64) + x tile (64x128) in LDS.

__global__ __launch_bounds__(256) void k_gemm_in(const float* __restrict__ x,
                                                 const float* __restrict__ W0,
                                                 const float* __restrict__ b0,
                                                 float* __restrict__ h,
                                                 float* __restrict__ h0) {
    __shared__ float sW[N_FEATS * HIDDEN];   // 32 KB
    __shared__ float sX[64 * N_FEATS];       // 32 KB
    const int v0 = blockIdx.x * 64;

    for (int idx = threadIdx.x; idx < N_FEATS * HIDDEN; idx += 256)
        sW[idx] = W0[idx];
    for (int idx = threadIdx.x; idx < 64 * N_FEATS; idx += 256) {
        int r = idx >> 7, k = idx & 127;
        int v = v0 + r;
        sX[idx] = (v < N_NODES) ? x[(size_t)v * N_FEATS + k] : 0.0f;
    }
    __syncthreads();

    const int c  = threadIdx.x & 63;
    const int r0 = threadIdx.x >> 6;   // 0..3
    float acc[16];
#pragma unroll
    for (int j = 0; j < 16; ++j) acc[j] = 0.0f;

    for (int k = 0; k < N_FEATS; ++k) {
        float w = sW[k * HIDDEN + c];
#pragma unroll
        for (int j = 0; j < 16; ++j)
            acc[j] += sX[(r0 + 4 * j) * N_FEATS + k] * w;
    }

    const float bias = b0[c];
#pragma unroll
    for (int j = 0; j < 16; ++j) {
        int v = v0 + r0 + 4 * j;
        if (v < N_NODES) {
            float val = fmaxf(acc[j] + bias, 0.0f);
            h[(size_t)v * HIDDEN + c]  = val;
            h0[(size_t)v * HIDDEN + c] = val;
        }
    }
}

// ---------------- support init: buf = (1-a)*dinv^2*h + a*h0 ----------------

__global__ __launch_bounds__(256) void k_support_init(const float* __restrict__ h,
                                                      const float* __restrict__ h0,
                                                      const float* __restrict__ dinv,
                                                      float* __restrict__ buf) {
    int idx = blockIdx.x * 256 + threadIdx.x;
    if (idx < N_NODES * HIDDEN) {
        int v = idx >> 6;
        float d = dinv[v];
        buf[idx] = (1.0f - ALPHA) * d * d * h[idx] + ALPHA * h0[idx];
    }
}

// ---------------- edge scatter: buf[col] += (1-a)*norm*h[row] ----------------
// one wave per edge; lane l handles feature l.

__global__ __launch_bounds__(256) void k_scatter(const int* __restrict__ row,
                                                 const int* __restrict__ col,
                                                 const float* __restrict__ norm,
                                                 const float* __restrict__ h,
                                                 float* __restrict__ buf) {
    const int lane = threadIdx.x & 63;
    const int wid  = (blockIdx.x * 256 + threadIdx.x) >> 6;
    const int nw   = (gridDim.x * 256) >> 6;
    for (int e = wid; e < N_EDGES; e += nw) {
        int r = row[e];
        int c = col[e];
        float nm = (1.0f - ALPHA) * norm[e];
        float val = nm * h[(size_t)r * HIDDEN + lane];
        unsafeAtomicAdd(&buf[(size_t)c * HIDDEN + lane], val);
    }
}

// ---------------- layer GEMM: hout = relu(beta*(S@W) + (1-beta)*S) ----------------
// 64 rows per block, W (64x64) + S tile (64x64) in LDS.

__global__ __launch_bounds__(256) void k_gemm_layer(const float* __restrict__ S,
                                                    const float* __restrict__ W,
                                                    float beta,
                                                    float* __restrict__ hout) {
    __shared__ float sW[HIDDEN * HIDDEN];   // 16 KB
    __shared__ float sS[64 * HIDDEN];       // 16 KB
    const int v0 = blockIdx.x * 64;

    for (int idx = threadIdx.x; idx < HIDDEN * HIDDEN; idx += 256)
        sW[idx] = W[idx];
    for (int idx = threadIdx.x; idx < 64 * HIDDEN; idx += 256) {
        int r = idx >> 6, k = idx & 63;
        int v = v0 + r;
        sS[idx] = (v < N_NODES) ? S[(size_t)v * HIDDEN + k] : 0.0f;
    }
    __syncthreads();

    const int c  = threadIdx.x & 63;
    const int r0 = threadIdx.x >> 6;
    float acc[16];
#pragma unroll
    for (int j = 0; j < 16; ++j) acc[j] = 0.0f;

    for (int k = 0; k < HIDDEN; ++k) {
        float w = sW[k * HIDDEN + c];
#pragma unroll
        for (int j = 0; j < 16; ++j)
            acc[j] += sS[(r0 + 4 * j) * HIDDEN + k] * w;
    }

#pragma unroll
    for (int j = 0; j < 16; ++j) {
        int r = r0 + 4 * j;
        int v = v0 + r;
        if (v < N_NODES) {
            float s   = sS[r * HIDDEN + c];
            float val = fmaxf(beta * acc[j] + (1.0f - beta) * s, 0.0f);
            hout[(size_t)v * HIDDEN + c] = val;
        }
    }
}

// ---------------- output GEMM: out = h @ W_out + b_out ----------------

__global__ __launch_bounds__(256) void k_gemm_out(const float* __restrict__ h,
                                                  const float* __restrict__ Wout,
                                                  const float* __restrict__ bout,
                                                  float* __restrict__ out) {
    __shared__ float sW[HIDDEN * N_CLASSES];  // 10 KB
    __shared__ float sH[64 * HIDDEN];         // 16 KB
    const int v0 = blockIdx.x * 64;

    for (int idx = threadIdx.x; idx < HIDDEN * N_CLASSES; idx += 256)
        sW[idx] = Wout[idx];
    for (int idx = threadIdx.x; idx < 64 * HIDDEN; idx += 256) {
        int r = idx >> 6, k = idx & 63;
        int v = v0 + r;
        sH[idx] = (v < N_NODES) ? h[(size_t)v * HIDDEN + k] : 0.0f;
    }
    __syncthreads();

    for (int idx = threadIdx.x; idx < 64 * N_CLASSES; idx += 256) {
        int r = idx / N_CLASSES, c = idx % N_CLASSES;
        int v = v0 + r;
        if (v < N_NODES) {
            float acc = bout[c];
#pragma unroll 8
            for (int k = 0; k < HIDDEN; ++k)
                acc += sH[r * HIDDEN + k] * sW[k * N_CLASSES + c];
            out[(size_t)v * N_CLASSES + c] = acc;
        }
    }
}

// ---------------- launch ----------------

extern "C" void kernel_launch(void* const* d_in, const int* in_sizes, int n_in,
                              void* d_out, int out_size, void* d_ws, size_t ws_size,
                              hipStream_t stream) {
    const float* x    = (const float*)d_in[0];
    const int*   ei   = (const int*)d_in[1];
    const float* W0   = (const float*)d_in[2];
    const float* b0   = (const float*)d_in[3];
    const float* Wl   = (const float*)d_in[4];
    const float* Wout = (const float*)d_in[5];
    const float* bout = (const float*)d_in[6];
    float* out = (float*)d_out;

    const int* row = ei;             // edge_index[0] = source
    const int* col = ei + N_EDGES;   // edge_index[1] = target

    char* ws = (char*)d_ws;
    size_t off = 0;
    auto alloc = [&](size_t bytes) -> void* {
        void* p = ws + off;
        off += (bytes + 255) & ~(size_t)255;
        return p;
    };
    float* dinv = (float*)alloc((size_t)N_NODES * 4);
    float* norm = (float*)alloc((size_t)N_EDGES * 4);
    float* h0   = (float*)alloc((size_t)N_NODES * HIDDEN * 4);
    float* h    = (float*)alloc((size_t)N_NODES * HIDDEN * 4);
    float* buf  = (float*)alloc((size_t)N_NODES * HIDDEN * 4);

    const int gN   = (N_NODES + 255) / 256;
    const int gE   = (N_EDGES + 255) / 256;
    const int gNH  = (N_NODES * HIDDEN + 255) / 256;
    const int gRow = (N_NODES + 63) / 64;

    // gcn_norm
    k_init_deg<<<gN, 256, 0, stream>>>(dinv);
    k_count_deg<<<gE, 256, 0, stream>>>(col, dinv);
    k_dinv<<<gN, 256, 0, stream>>>(dinv);
    k_norm<<<gE, 256, 0, stream>>>(row, col, dinv, norm);

    // h = relu(x@W0 + b0); h0 = h
    k_gemm_in<<<gRow, 256, 0, stream>>>(x, W0, b0, h, h0);

    for (int i = 0; i < N_LAYERS; ++i) {
        float beta = logf(LAMDA / (float)(i + 1) + 1.0f);
        // buf = (1-a)*selfloop + a*h0
        k_support_init<<<gNH, 256, 0, stream>>>(h, h0, dinv, buf);
        // buf += (1-a)*norm*h[row] scattered to col
        k_scatter<<<2048, 256, 0, stream>>>(row, col, norm, h, buf);
        // h = relu(beta*(buf@Wl[i]) + (1-beta)*buf)
        k_gemm_layer<<<gRow, 256, 0, stream>>>(buf, Wl + (size_t)i * HIDDEN * HIDDEN,
                                               beta, h);
    }

    // out = h @ W_out + b_out
    k_gemm_out<<<gRow, 256, 0, stream>>>(h, Wout, bout, out);
}

// Round 2
// 1078.496 us; speedup vs baseline: 3.0834x; 3.0834x over previous
//
#include <hip/hip_runtime.h>
#include <cmath>

#define N_NODES   100000
#define N_EDGES   1600000
#define N_FEATS   128
#define HIDDEN    64
#define N_CLASSES 40
#define N_LAYERS  8
#define ALPHA     0.1f
#define LAMDA     0.5f

#define SCAN_ITEMS 8
#define SCAN_BLK   256
#define SCAN_TILE  (SCAN_ITEMS * SCAN_BLK)                  // 2048
#define SCAN_NBLK  ((N_NODES + SCAN_TILE - 1) / SCAN_TILE)  // 49

// ---------------- CSR build ----------------

__global__ __launch_bounds__(256) void k_zero_deg(int* __restrict__ deg) {
    int i = blockIdx.x * 256 + threadIdx.x;
    if (i < N_NODES) deg[i] = 0;
}

__global__ __launch_bounds__(256) void k_count_deg(const int* __restrict__ col,
                                                   int* __restrict__ deg) {
    int e = blockIdx.x * 256 + threadIdx.x;
    if (e < N_EDGES) atomicAdd(&deg[col[e]], 1);
}

// block-level exclusive scan of deg -> rowptr (partial), block totals -> bsum
__global__ __launch_bounds__(SCAN_BLK) void k_scan1(const int* __restrict__ deg,
                                                    int* __restrict__ rowptr,
                                                    int* __restrict__ bsum) {
    __shared__ int sc[SCAN_BLK];
    const int t = threadIdx.x;
    const int base = blockIdx.x * SCAN_TILE + t * SCAN_ITEMS;
    int v[SCAN_ITEMS];
    int tsum = 0;
#pragma unroll
    for (int j = 0; j < SCAN_ITEMS; ++j) {
        v[j] = (base + j < N_NODES) ? deg[base + j] : 0;
        tsum += v[j];
    }
    sc[t] = tsum;
    __syncthreads();
    for (int off = 1; off < SCAN_BLK; off <<= 1) {
        int x = (t >= off) ? sc[t - off] : 0;
        __syncthreads();
        sc[t] += x;
        __syncthreads();
    }
    int run = sc[t] - tsum;   // exclusive prefix of this thread within block
#pragma unroll
    for (int j = 0; j < SCAN_ITEMS; ++j) {
        if (base + j < N_NODES) rowptr[base + j] = run;
        run += v[j];
    }
    if (t == SCAN_BLK - 1) bsum[blockIdx.x] = sc[SCAN_BLK - 1];
}

// single-block exclusive scan of the 49 block sums
__global__ __launch_bounds__(SCAN_BLK) void k_scan2(int* __restrict__ bsum) {
    __shared__ int sc[SCAN_BLK];
    const int t = threadIdx.x;
    int v = (t < SCAN_NBLK) ? bsum[t] : 0;
    sc[t] = v;
    __syncthreads();
    for (int off = 1; off < SCAN_BLK; off <<= 1) {
        int x = (t >= off) ? sc[t - off] : 0;
        __syncthreads();
        sc[t] += x;
        __syncthreads();
    }
    if (t < SCAN_NBLK) bsum[t] = sc[t] - v;   // exclusive
}

// add block offsets; copy start offsets into cursor; set rowptr[N]
__global__ __launch_bounds__(256) void k_scan3(int* __restrict__ rowptr,
                                               const int* __restrict__ bsum,
                                               int* __restrict__ cursor) {
    int i = blockIdx.x * 256 + threadIdx.x;
    if (i < N_NODES) {
        int r = rowptr[i] + bsum[i / SCAN_TILE];
        rowptr[i] = r;
        cursor[i] = r;
    }
    if (i == 0) rowptr[N_NODES] = N_EDGES;
}

__global__ __launch_bounds__(256) void k_dinv(const int* __restrict__ deg,
                                              float* __restrict__ dinv) {
    int i = blockIdx.x * 256 + threadIdx.x;
    if (i < N_NODES) dinv[i] = rsqrtf(1.0f + (float)deg[i]);   // +1 self-loop
}

__global__ __launch_bounds__(256) void k_fill(const int* __restrict__ row,
                                              const int* __restrict__ col,
                                              const float* __restrict__ dinv,
                                              int* __restrict__ cursor,
                                              int* __restrict__ csr_src,
                                              float* __restrict__ csr_w) {
    int e = blockIdx.x * 256 + threadIdx.x;
    if (e < N_EDGES) {
        int r = row[e], c = col[e];
        int pos = atomicAdd(&cursor[c], 1);
        csr_src[pos] = r;
        csr_w[pos]   = (1.0f - ALPHA) * dinv[r] * dinv[c];
    }
}

// ---------------- input GEMM: h = relu(x @ W0 + b0), h0 = h ----------------

__global__ __launch_bounds__(256) void k_gemm_in(const float* __restrict__ x,
                                                 const float* __restrict__ W0,
                                                 const float* __restrict__ b0,
                                                 float* __restrict__ h,
                                                 float* __restrict__ h0) {
    __shared__ float sW[N_FEATS * HIDDEN];   // 32 KB
    __shared__ float sX[64 * N_FEATS];       // 32 KB
    const int v0 = blockIdx.x * 64;
    const bool full = (v0 + 64 <= N_NODES);

    const float4* W4 = (const float4*)W0;
    for (int idx = threadIdx.x; idx < (N_FEATS * HIDDEN) / 4; idx += 256)
        ((float4*)sW)[idx] = W4[idx];
    if (full) {
        const float4* X4 = (const float4*)(x + (size_t)v0 * N_FEATS);
        for (int idx = threadIdx.x; idx < (64 * N_FEATS) / 4; idx += 256)
            ((float4*)sX)[idx] = X4[idx];
    } else {
        for (int idx = threadIdx.x; idx < 64 * N_FEATS; idx += 256) {
            int r = idx >> 7, k = idx & 127;
            int v = v0 + r;
            sX[idx] = (v < N_NODES) ? x[(size_t)v * N_FEATS + k] : 0.0f;
        }
    }
    __syncthreads();

    const int c  = threadIdx.x & 63;
    const int r0 = threadIdx.x >> 6;   // 0..3
    float acc[16];
#pragma unroll
    for (int j = 0; j < 16; ++j) acc[j] = 0.0f;

    for (int k = 0; k < N_FEATS; ++k) {
        float w = sW[k * HIDDEN + c];
#pragma unroll
        for (int j = 0; j < 16; ++j)
            acc[j] += sX[(r0 + 4 * j) * N_FEATS + k] * w;
    }

    const float bias = b0[c];
#pragma unroll
    for (int j = 0; j < 16; ++j) {
        int v = v0 + r0 + 4 * j;
        if (v < N_NODES) {
            float val = fmaxf(acc[j] + bias, 0.0f);
            h[(size_t)v * HIDDEN + c]  = val;
            h0[(size_t)v * HIDDEN + c] = val;
        }
    }
}

// ---------------- fused SpMM: buf = (1-a)*A_hat*h + a*h0 ----------------
// one wave per node; lane l owns feature l; indices batch-loaded + shfl-bcast.

__global__ __launch_bounds__(256) void k_spmm(const int* __restrict__ rowptr,
                                              const int* __restrict__ csr_src,
                                              const float* __restrict__ csr_w,
                                              const float* __restrict__ dinv,
                                              const float* __restrict__ h,
                                              const float* __restrict__ h0,
                                              float* __restrict__ buf) {
    const int lane = threadIdx.x & 63;
    const int node = (blockIdx.x * 256 + threadIdx.x) >> 6;
    if (node >= N_NODES) return;

    const int e0 = rowptr[node];
    const int e1 = rowptr[node + 1];
    const float d = dinv[node];
    const size_t ib = (size_t)node * HIDDEN + lane;

    // self-loop + residual
    float acc = (1.0f - ALPHA) * d * d * h[ib] + ALPHA * h0[ib];

    for (int eb = e0; eb < e1; eb += 64) {
        int n = e1 - eb;
        if (n > 64) n = 64;
        int   idx = 0;
        float w   = 0.0f;
        if (lane < n) {
            idx = csr_src[eb + lane];
            w   = csr_w[eb + lane];
        }
        int j = 0;
        for (; j + 4 <= n; j += 4) {
            int s0 = __shfl(idx, j),     s1 = __shfl(idx, j + 1);
            int s2 = __shfl(idx, j + 2), s3 = __shfl(idx, j + 3);
            float w0 = __shfl(w, j),     w1 = __shfl(w, j + 1);
            float w2 = __shfl(w, j + 2), w3 = __shfl(w, j + 3);
            float x0 = h[(size_t)s0 * HIDDEN + lane];
            float x1 = h[(size_t)s1 * HIDDEN + lane];
            float x2 = h[(size_t)s2 * HIDDEN + lane];
            float x3 = h[(size_t)s3 * HIDDEN + lane];
            acc += w0 * x0;
            acc += w1 * x1;
            acc += w2 * x2;
            acc += w3 * x3;
        }
        for (; j < n; ++j) {
            int   s  = __shfl(idx, j);
            float ww = __shfl(w, j);
            acc += ww * h[(size_t)s * HIDDEN + lane];
        }
    }
    buf[ib] = acc;
}

// ---------------- layer GEMM: hout = relu(beta*(S@W) + (1-beta)*S) ----------------

__global__ __launch_bounds__(256) void k_gemm_layer(const float* __restrict__ S,
                                                    const float* __restrict__ W,
                                                    float beta,
                                                    float* __restrict__ hout) {
    __shared__ float sW[HIDDEN * HIDDEN];   // 16 KB
    __shared__ float sS[64 * HIDDEN];       // 16 KB
    const int v0 = blockIdx.x * 64;
    const bool full = (v0 + 64 <= N_NODES);

    const float4* W4 = (const float4*)W;
    for (int idx = threadIdx.x; idx < (HIDDEN * HIDDEN) / 4; idx += 256)
        ((float4*)sW)[idx] = W4[idx];
    if (full) {
        const float4* S4 = (const float4*)(S + (size_t)v0 * HIDDEN);
        for (int idx = threadIdx.x; idx < (64 * HIDDEN) / 4; idx += 256)
            ((float4*)sS)[idx] = S4[idx];
    } else {
        for (int idx = threadIdx.x; idx < 64 * HIDDEN; idx += 256) {
            int r = idx >> 6, k = idx & 63;
            int v = v0 + r;
            sS[idx] = (v < N_NODES) ? S[(size_t)v * HIDDEN + k] : 0.0f;
        }
    }
    __syncthreads();

    const int c  = threadIdx.x & 63;
    const int r0 = threadIdx.x >> 6;
    float acc[16];
#pragma unroll
    for (int j = 0; j < 16; ++j) acc[j] = 0.0f;

    for (int k = 0; k < HIDDEN; ++k) {
        float w = sW[k * HIDDEN + c];
#pragma unroll
        for (int j = 0; j < 16; ++j)
            acc[j] += sS[(r0 + 4 * j) * HIDDEN + k] * w;
    }

#pragma unroll
    for (int j = 0; j < 16; ++j) {
        int r = r0 + 4 * j;
        int v = v0 + r;
        if (v < N_NODES) {
            float s   = sS[r * HIDDEN + c];
            float val = fmaxf(beta * acc[j] + (1.0f - beta) * s, 0.0f);
            hout[(size_t)v * HIDDEN + c] = val;
        }
    }
}

// ---------------- output GEMM: out = h @ W_out + b_out ----------------

__global__ __launch_bounds__(256) void k_gemm_out(const float* __restrict__ h,
                                                  const float* __restrict__ Wout,
                                                  const float* __restrict__ bout,
                                                  float* __restrict__ out) {
    __shared__ float sW[HIDDEN * N_CLASSES];  // 10 KB
    __shared__ float sH[64 * HIDDEN];         // 16 KB
    const int v0 = blockIdx.x * 64;

    for (int idx = threadIdx.x; idx < HIDDEN * N_CLASSES; idx += 256)
        sW[idx] = Wout[idx];
    for (int idx = threadIdx.x; idx < 64 * HIDDEN; idx += 256) {
        int r = idx >> 6, k = idx & 63;
        int v = v0 + r;
        sH[idx] = (v < N_NODES) ? h[(size_t)v * HIDDEN + k] : 0.0f;
    }
    __syncthreads();

    for (int idx = threadIdx.x; idx < 64 * N_CLASSES; idx += 256) {
        int r = idx / N_CLASSES, c = idx % N_CLASSES;
        int v = v0 + r;
        if (v < N_NODES) {
            float acc = bout[c];
#pragma unroll 8
            for (int k = 0; k < HIDDEN; ++k)
                acc += sH[r * HIDDEN + k] * sW[k * N_CLASSES + c];
            out[(size_t)v * N_CLASSES + c] = acc;
        }
    }
}

// ---------------- launch ----------------

extern "C" void kernel_launch(void* const* d_in, const int* in_sizes, int n_in,
                              void* d_out, int out_size, void* d_ws, size_t ws_size,
                              hipStream_t stream) {
    const float* x    = (const float*)d_in[0];
    const int*   ei   = (const int*)d_in[1];
    const float* W0   = (const float*)d_in[2];
    const float* b0   = (const float*)d_in[3];
    const float* Wl   = (const float*)d_in[4];
    const float* Wout = (const float*)d_in[5];
    const float* bout = (const float*)d_in[6];
    float* out = (float*)d_out;

    const int* row = ei;             // edge_index[0] = source
    const int* col = ei + N_EDGES;   // edge_index[1] = target

    char* ws = (char*)d_ws;
    size_t off = 0;
    auto alloc = [&](size_t bytes) -> void* {
        void* p = ws + off;
        off += (bytes + 255) & ~(size_t)255;
        return p;
    };
    int*   deg     = (int*)alloc((size_t)N_NODES * 4);
    int*   rowptr  = (int*)alloc((size_t)(N_NODES + 1) * 4);
    int*   cursor  = (int*)alloc((size_t)N_NODES * 4);
    int*   bsum    = (int*)alloc((size_t)SCAN_NBLK * 4);
    int*   csr_src = (int*)alloc((size_t)N_EDGES * 4);
    float* csr_w   = (float*)alloc((size_t)N_EDGES * 4);
    float* dinv    = (float*)alloc((size_t)N_NODES * 4);
    float* h0      = (float*)alloc((size_t)N_NODES * HIDDEN * 4);
    float* hA      = (float*)alloc((size_t)N_NODES * HIDDEN * 4);
    float* hB      = (float*)alloc((size_t)N_NODES * HIDDEN * 4);

    const int gN   = (N_NODES + 255) / 256;
    const int gE   = (N_EDGES + 255) / 256;
    const int gRow = (N_NODES + 63) / 64;
    const int gSpm = (N_NODES * 64 + 255) / 256;   // wave per node

    // CSR build (by target node)
    k_zero_deg <<<gN, 256, 0, stream>>>(deg);
    k_count_deg<<<gE, 256, 0, stream>>>(col, deg);
    k_scan1    <<<SCAN_NBLK, SCAN_BLK, 0, stream>>>(deg, rowptr, bsum);
    k_scan2    <<<1, SCAN_BLK, 0, stream>>>(bsum);
    k_scan3    <<<gN, 256, 0, stream>>>(rowptr, bsum, cursor);
    k_dinv     <<<gN, 256, 0, stream>>>(deg, dinv);
    k_fill     <<<gE, 256, 0, stream>>>(row, col, dinv, cursor, csr_src, csr_w);

    // h = relu(x@W0 + b0); h0 = h
    k_gemm_in<<<gRow, 256, 0, stream>>>(x, W0, b0, hA, h0);

    float* h   = hA;
    float* buf = hB;
    for (int i = 0; i < N_LAYERS; ++i) {
        float beta = logf(LAMDA / (float)(i + 1) + 1.0f);
        // buf = (1-a)*A_hat*h + a*h0   (self-loop + residual fused)
        k_spmm<<<gSpm, 256, 0, stream>>>(rowptr, csr_src, csr_w, dinv, h, h0, buf);
        // h = relu(beta*(buf@Wl[i]) + (1-beta)*buf)  -> write into h (ping-pong)
        k_gemm_layer<<<gRow, 256, 0, stream>>>(buf, Wl + (size_t)i * HIDDEN * HIDDEN,
                                               beta, h);
    }

    // out = h @ W_out + b_out
    k_gemm_out<<<gRow, 256, 0, stream>>>(h, Wout, bout, out);
}